// Round 2
// baseline (1470.991 us; speedup 1.0000x reference)
//
#include <hip/hip_runtime.h>

// RFNetwork recurrence, restructured:
//   out_t = (W + P) @ x_t              (P = out_in_p; in_in_p is dead code)
//   P     = colrenorm(rowrenorm(P + lambda * outer(out_t, x_t)))
// One-step-lazy column scale: LDS holds P_tilde = pre-col-renorm true values
// of the previous step, plus f_j = previous step's column factor (<= 1).
//   pass1: out_i = (W x)_i + sum_j Pt_ij f_j x_j ; R_i = sum_j Pt_ij f_j
//          r_i from R1_i = R_i + lambda*out_i*sum(x)
//   pass2: v_ij = r_i*(Pt_ij*f_j + lambda*out_i*x_j)   [true pre-col values]
//          store v as new Pt; partial colsums -> Spart[parity][block][j]
//   grid barrier;每 block reduces all colsums itself; f_j = s>1 ? 1/s : 1
// No divisions by state, no cumulative scale -> no under/overflow.

#define T_STEPS 128
#define N 1024
#define NB 64          // blocks
#define RPB 16         // rows of P per block (N/NB)
#define NT 1024        // threads per block (16 waves)
#define LMBDA 0.01f

__device__ __forceinline__ float wred(float v) {
#pragma unroll
  for (int off = 32; off; off >>= 1) v += __shfl_xor(v, off, 64);
  return v;  // all lanes hold the sum
}

__device__ __forceinline__ void gbar(unsigned* cnt, unsigned* gen) {
  __syncthreads();
  if (threadIdx.x == 0) {
    __threadfence();  // release: block's prior global stores -> device scope
    unsigned g = __hip_atomic_load(gen, __ATOMIC_RELAXED, __HIP_MEMORY_SCOPE_AGENT);
    unsigned prev = __hip_atomic_fetch_add(cnt, 1u, __ATOMIC_ACQ_REL, __HIP_MEMORY_SCOPE_AGENT);
    if (prev == NB - 1u) {
      __hip_atomic_store(cnt, 0u, __ATOMIC_RELAXED, __HIP_MEMORY_SCOPE_AGENT);
      __hip_atomic_store(gen, g + 1u, __ATOMIC_RELEASE, __HIP_MEMORY_SCOPE_AGENT);
    } else {
      unsigned cur;
      do {
        __builtin_amdgcn_s_sleep(1);
        cur = __hip_atomic_load(gen, __ATOMIC_RELAXED, __HIP_MEMORY_SCOPE_AGENT);
      } while (cur == g);
    }
    __threadfence();  // acquire: invalidate stale cached lines
  }
  __syncthreads();
}

__global__ __launch_bounds__(NT) void rf_step_kernel(
    const float* __restrict__ X,      // [T][N] inputs
    const float* __restrict__ W,      // [N][N] out_in_fixed
    float* __restrict__ OUT,          // [T][N]
    float* __restrict__ Spart,        // [2][NB][N] partial colsums (dbuf)
    unsigned* __restrict__ cnt, unsigned* __restrict__ gen) {
  __shared__ float P_l[RPB][N];   // 64 KB: this block's rows of P_tilde
  __shared__ float f_l[N];        // previous step's column factor (<=1)
  __shared__ float xb[N];         // staged x_t
  __shared__ float outl[RPB];     // lambda*out per local row
  __shared__ float rf_l[RPB];     // row renorm factor per local row

  const int tid = threadIdx.x;
  const int b = blockIdx.x;
  const int w = tid >> 6;   // wave id == local row in pass 1
  const int l = tid & 63;   // lane
  const int row = b * RPB + w;

  // ---- init state ----
#pragma unroll
  for (int r = 0; r < RPB; ++r) P_l[r][tid] = 0.0f;
  f_l[tid] = 1.0f;
  xb[tid] = X[tid];  // x[0]

  // W row fragment in registers: lane l covers j = 4l + 256k
  float4 wr[4];
#pragma unroll
  for (int k = 0; k < 4; ++k)
    wr[k] = *reinterpret_cast<const float4*>(&W[(size_t)row * N + 4 * l + 256 * k]);

  __syncthreads();

  for (int t = 0; t < T_STEPS; ++t) {
    // ---- pass 1: out_i, true rowsum R_i, sum(x) (3 fused reductions) ----
    float a_out = 0.f, a_R = 0.f, a_sx = 0.f;
#pragma unroll
    for (int k = 0; k < 4; ++k) {
      const int j = 4 * l + 256 * k;
      float4 p = *reinterpret_cast<const float4*>(&P_l[w][j]);
      float4 ff = *reinterpret_cast<const float4*>(&f_l[j]);
      float4 xx = *reinterpret_cast<const float4*>(&xb[j]);
      float pc0 = p.x * ff.x, pc1 = p.y * ff.y, pc2 = p.z * ff.z, pc3 = p.w * ff.w;
      a_out += (pc0 + wr[k].x) * xx.x + (pc1 + wr[k].y) * xx.y +
               (pc2 + wr[k].z) * xx.z + (pc3 + wr[k].w) * xx.w;
      a_R += pc0 + pc1 + pc2 + pc3;
      a_sx += xx.x + xx.y + xx.z + xx.w;
    }
    float out = wred(a_out);
    float R = wred(a_R);
    float sx = wred(a_sx);
    if (l == 0) {
      OUT[t * N + row] = out;
      float R1 = R + LMBDA * out * sx;          // rowsum after rank-1 update
      rf_l[w] = (R1 > 1.0f) ? 1.0f / R1 : 1.0f; // MAX_POST = 1
      outl[w] = LMBDA * out;
    }
    __syncthreads();

    // ---- pass 2: apply f, rank-1 update, row renorm, partial colsums ----
    float xnext = (t + 1 < T_STEPS) ? X[(t + 1) * N + tid] : 0.f;
    const float fc = f_l[tid];
    const float x = xb[tid];
    float cs = 0.f;
#pragma unroll
    for (int r = 0; r < RPB; ++r) {
      float v = rf_l[r] * (P_l[r][tid] * fc + outl[r] * x);
      P_l[r][tid] = v;
      cs += v;
    }
    float* Sp = Spart + (size_t)(t & 1) * NB * N;
    Sp[b * N + tid] = cs;  // coalesced 4KB store
    xb[tid] = xnext;       // own slot; pass-1 readers are behind the barrier

    gbar(cnt, gen);

    // ---- every block reduces all column sums (coalesced over tid) ----
    float s = 0.f;
#pragma unroll 8
    for (int bb = 0; bb < NB; ++bb) s += Sp[bb * N + tid];
    f_l[tid] = (s > 1.0f) ? 1.0f / s : 1.0f;  // MAX_PRE = 1
    __syncthreads();
  }
}

extern "C" void kernel_launch(void* const* d_in, const int* in_sizes, int n_in,
                              void* d_out, int out_size, void* d_ws, size_t ws_size,
                              hipStream_t stream) {
  const float* X = (const float*)d_in[0];   // inputs [128][1024]
  const float* W = (const float*)d_in[2];   // out_in_fixed [1024][1024]
  float* OUT = (float*)d_out;               // [128][1024] f32

  char* ws = (char*)d_ws;
  float* Spart = (float*)ws;                               // 2*NB*N*4 = 512 KB
  unsigned* ctrl = (unsigned*)(ws + (size_t)2 * NB * N * 4);

  // barrier control block must be zero at kernel start (ws is poisoned 0xAA)
  hipMemsetAsync(ctrl, 0, 2 * sizeof(unsigned), stream);

  hipLaunchKernelGGL(rf_step_kernel, dim3(NB), dim3(NT), 0, stream,
                     X, W, OUT, Spart, ctrl, ctrl + 1);
}

// Round 3
// 1355.742 us; speedup vs baseline: 1.0850x; 1.0850x over previous
//
#include <hip/hip_runtime.h>

// RFNetwork recurrence, restructured:
//   out_t = (W + P) @ x_t              (P = out_in_p; in_in_p is dead code)
//   P     = colrenorm(rowrenorm(P + lambda * outer(out_t, x_t)))
// One-step-lazy column scale: LDS holds P_tilde = pre-col-renorm true values
// of the previous step, plus f_j = previous step's column factor (<= 1).
//   pass1: out_i = (W x)_i + sum_j Pt_ij f_j x_j ; R_i = sum_j Pt_ij f_j
//          r_i from R1_i = R_i + lambda*out_i*sum(x)
//   pass2: v_ij = r_i*(Pt_ij*f_j + lambda*out_i*x_j)   [true pre-col values]
//          store v as new Pt; partial colsums -> Spart[parity][block][j]
//   flag barrier; every block reduces all colsums itself; f_j = s>1 ? 1/s : 1
//
// Barrier = all-report/all-poll flags (NO central atomic RMW chain):
//   block b: release-store flags[b]=t+1; wave0 polls all 64 flags with one
//   64-lane load until __all(flags >= t+1). Monotone targets -> no reset.
//   Spart double-buffered by step parity; a same-parity overwrite at t+2 is
//   gated on flags>=t+2 which each block sets only after its parity reads
//   from step t finished -> no read/write race under block skew.

#define T_STEPS 128
#define N 1024
#define NB 64          // blocks
#define RPB 16         // rows of P per block (N/NB)
#define NT 1024        // threads per block (16 waves)
#define LMBDA 0.01f

__device__ __forceinline__ float wred(float v) {
#pragma unroll
  for (int off = 32; off; off >>= 1) v += __shfl_xor(v, off, 64);
  return v;  // all lanes hold the sum
}

__global__ __launch_bounds__(NT) void rf_step_kernel(
    const float* __restrict__ X,      // [T][N] inputs
    const float* __restrict__ W,      // [N][N] out_in_fixed
    float* __restrict__ OUT,          // [T][N]
    float* __restrict__ Spart,        // [2][NB][N] partial colsums (dbuf)
    unsigned* __restrict__ flags) {   // [NB] arrival flags, monotone
  __shared__ float P_l[RPB][N];   // 64 KB: this block's rows of P_tilde
  __shared__ float f_l[N];        // previous step's column factor (<=1)
  __shared__ float xb[N];         // staged x_t
  __shared__ float outl[RPB];     // lambda*out per local row
  __shared__ float rf_l[RPB];     // row renorm factor per local row

  const int tid = threadIdx.x;
  const int b = blockIdx.x;
  const int w = tid >> 6;   // wave id == local row in pass 1
  const int l = tid & 63;   // lane
  const int row = b * RPB + w;

  // ---- init state ----
#pragma unroll
  for (int r = 0; r < RPB; ++r) P_l[r][tid] = 0.0f;
  f_l[tid] = 1.0f;
  xb[tid] = X[tid];  // x[0]

  // W row fragment in registers: lane l covers j = 4l + 256k
  float4 wr[4];
#pragma unroll
  for (int k = 0; k < 4; ++k)
    wr[k] = *reinterpret_cast<const float4*>(&W[(size_t)row * N + 4 * l + 256 * k]);

  __syncthreads();

  for (int t = 0; t < T_STEPS; ++t) {
    // ---- pass 1: out_i, true rowsum R_i, sum(x) (3 fused reductions) ----
    float a_out = 0.f, a_R = 0.f, a_sx = 0.f;
#pragma unroll
    for (int k = 0; k < 4; ++k) {
      const int j = 4 * l + 256 * k;
      float4 p = *reinterpret_cast<const float4*>(&P_l[w][j]);
      float4 ff = *reinterpret_cast<const float4*>(&f_l[j]);
      float4 xx = *reinterpret_cast<const float4*>(&xb[j]);
      float pc0 = p.x * ff.x, pc1 = p.y * ff.y, pc2 = p.z * ff.z, pc3 = p.w * ff.w;
      a_out += (pc0 + wr[k].x) * xx.x + (pc1 + wr[k].y) * xx.y +
               (pc2 + wr[k].z) * xx.z + (pc3 + wr[k].w) * xx.w;
      a_R += pc0 + pc1 + pc2 + pc3;
      a_sx += xx.x + xx.y + xx.z + xx.w;
    }
    float out = wred(a_out);
    float R = wred(a_R);
    float sx = wred(a_sx);
    if (l == 0) {
      OUT[t * N + row] = out;
      float R1 = R + LMBDA * out * sx;          // rowsum after rank-1 update
      rf_l[w] = (R1 > 1.0f) ? 1.0f / R1 : 1.0f; // MAX_POST = 1
      outl[w] = LMBDA * out;
    }
    __syncthreads();

    // ---- pass 2: apply f, rank-1 update, row renorm, partial colsums ----
    float xnext = (t + 1 < T_STEPS) ? X[(t + 1) * N + tid] : 0.f;
    const float fc = f_l[tid];
    const float x = xb[tid];
    float cs = 0.f;
#pragma unroll
    for (int r = 0; r < RPB; ++r) {
      float v = rf_l[r] * (P_l[r][tid] * fc + outl[r] * x);
      P_l[r][tid] = v;
      cs += v;
    }
    float* Sp = Spart + (size_t)(t & 1) * NB * N;
    Sp[b * N + tid] = cs;  // coalesced 4KB store
    xb[tid] = xnext;       // own slot; pass-1 readers are behind the barrier

    // ---- flag barrier: report arrival, poll all 64 flags ----
    __syncthreads();  // all Spart stores issued (vmcnt drained by barrier)
    if (w == 0) {
      const unsigned target = t + 1u;
      if (l == 0) {
        __threadfence();  // release: flush this XCD's L2 so Spart is visible
        __hip_atomic_store(&flags[b], target, __ATOMIC_RELEASE,
                           __HIP_MEMORY_SCOPE_AGENT);
      }
      for (;;) {
        unsigned v = __hip_atomic_load(&flags[l], __ATOMIC_RELAXED,
                                       __HIP_MEMORY_SCOPE_AGENT);
        if (__all(v >= target)) break;
        __builtin_amdgcn_s_sleep(1);
      }
      if (l == 0) __threadfence();  // acquire: invalidate stale L1/L2 lines
    }
    __syncthreads();

    // ---- every block reduces all column sums (coalesced over tid) ----
    float s = 0.f;
#pragma unroll 16
    for (int bb = 0; bb < NB; ++bb) s += Sp[bb * N + tid];
    f_l[tid] = (s > 1.0f) ? 1.0f / s : 1.0f;  // MAX_PRE = 1
    __syncthreads();
  }
}

extern "C" void kernel_launch(void* const* d_in, const int* in_sizes, int n_in,
                              void* d_out, int out_size, void* d_ws, size_t ws_size,
                              hipStream_t stream) {
  const float* X = (const float*)d_in[0];   // inputs [128][1024]
  const float* W = (const float*)d_in[2];   // out_in_fixed [1024][1024]
  float* OUT = (float*)d_out;               // [128][1024] f32

  char* ws = (char*)d_ws;
  float* Spart = (float*)ws;                               // 2*NB*N*4 = 512 KB
  unsigned* flags = (unsigned*)(ws + (size_t)2 * NB * N * 4);

  // flags must start at 0 each launch (ws is poisoned 0xAA once, and replays
  // must be deterministic) — async memset is graph-capture-safe.
  hipMemsetAsync(flags, 0, NB * sizeof(unsigned), stream);

  hipLaunchKernelGGL(rf_step_kernel, dim3(NB), dim3(NT), 0, stream,
                     X, W, OUT, Spart, flags);
}

// Round 4
// 935.238 us; speedup vs baseline: 1.5729x; 1.4496x over previous
//
#include <hip/hip_runtime.h>

// RFNetwork recurrence (in_in_p is dead code; P = out_in_p):
//   out_t = (W + P) @ x_t ;  P = colrenorm(rowrenorm(P + l*outer(out,x)))
// One-step-lazy column factor f_j (<=1, no accumulation):
//   pass1 (wave=row): out_i = (W x)_i + sum_j Pt_ij f_j x_j ; R_i = sum_j Pt_ij f_j
//                     r_i from R1_i = R_i + l*out_i*sx   (sx precomputed per t)
//   pass2 (thread=4cols x 4rows, float4): v = r_i*(Pt f + l*out_i*x); colsum partials
//   flag barrier (sc1-coherent, no fences); every block re-reduces colsums (float4,
//   sc1 LLC loads); f_j = s>1 ? 1/s : 1
// Cross-block data NEVER sits in L2: all Spart/flag traffic uses sc0|sc1
// (LLC-coherent) ops, so no buffer_wbl2/buffer_inv fences are needed.
// Release ordering: __syncthreads drains each wave's vmcnt before the flag store.

typedef float f32x4 __attribute__((ext_vector_type(4)));

#define T_STEPS 128
#define N 1024
#define N4 256         // N/4
#define NB 64          // blocks
#define RPB 16         // rows per block
#define NT 1024        // threads per block (16 waves)
#define LMBDA 0.01f

__device__ __forceinline__ float wred(float v) {
#pragma unroll
  for (int off = 32; off; off >>= 1) v += __shfl_xor(v, off, 64);
  return v;  // all lanes hold the sum
}

__global__ __launch_bounds__(NT) void rf_step_kernel(
    const float* __restrict__ X,      // [T][N]
    const float* __restrict__ W,      // [N][N]
    float* __restrict__ OUT,          // [T][N]
    float* __restrict__ Spart,        // [2][NB][N] partial colsums (dbuf)
    unsigned* __restrict__ flags) {   // [NB] monotone arrival flags
  __shared__ f32x4 P4[RPB][N4];   // 64 KB P_tilde
  __shared__ f32x4 F4[N4];        // 4 KB  column factor f
  __shared__ f32x4 SL[4][N4];     // 16 KB cross-group combine buffer
  __shared__ float outl[RPB];
  __shared__ float rf_l[RPB];
  __shared__ float sxAll[T_STEPS];

  const int tid = threadIdx.x;
  const int b = blockIdx.x;
  const int w = tid >> 6;    // wave id == local row (pass1)
  const int l = tid & 63;    // lane
  const int g = tid >> 8;    // row-group (pass2/colsum)
  const int c4 = tid & 255;  // float4-column (pass2/colsum)
  const int row = b * RPB + w;

  const f32x4* X4 = (const f32x4*)X;
  const f32x4* W4 = (const f32x4*)W;

  // ---- init ----
#pragma unroll
  for (int k = 0; k < 4; ++k) ((f32x4*)P4)[tid + k * NT] = f32x4{0.f, 0.f, 0.f, 0.f};
  if (tid < N4) F4[tid] = f32x4{1.f, 1.f, 1.f, 1.f};

  // sx for every step up front (X is fixed input): wave w handles t = w, w+16, ...
  for (int tt = w; tt < T_STEPS; tt += 16) {
    float a = 0.f;
#pragma unroll
    for (int k = 0; k < 4; ++k) {
      f32x4 x = X4[tt * N4 + l + 64 * k];
      a += x.x + x.y + x.z + x.w;
    }
    a = wred(a);
    if (l == 0) sxAll[tt] = a;
  }

  // W row fragment in registers: lane l covers float4-cols l+64k
  f32x4 wr[4];
#pragma unroll
  for (int k = 0; k < 4; ++k) wr[k] = W4[(size_t)row * N4 + l + 64 * k];

  __syncthreads();

  for (int t = 0; t < T_STEPS; ++t) {
    // ---- pass 1: out_i and R_i (x from global/L1, P,f from LDS) ----
    float a_out = 0.f, a_R = 0.f;
#pragma unroll
    for (int k = 0; k < 4; ++k) {
      const int j4 = l + 64 * k;
      f32x4 p = P4[w][j4];
      f32x4 f = F4[j4];
      f32x4 x = X4[t * N4 + j4];
      f32x4 pf = p * f;
      a_R += pf.x + pf.y + pf.z + pf.w;
      f32x4 s = (pf + wr[k]) * x;
      a_out += s.x + s.y + s.z + s.w;
    }
    float out = wred(a_out);
    float R = wred(a_R);
    if (l == 0) {
      OUT[t * N + row] = out;
      float R1 = R + LMBDA * out * sxAll[t];
      rf_l[w] = (R1 > 1.0f) ? 1.0f / R1 : 1.0f;  // MAX_POST = 1
      outl[w] = LMBDA * out;
    }
    if (t == T_STEPS - 1) break;  // state update past last output is dead work
    __syncthreads();

    // ---- pass 2: apply f, rank-1 update, row renorm (float4, 4 rows/thread) ----
    {
      f32x4 fc = F4[c4];
      f32x4 xt = X4[t * N4 + c4];
      f32x4 acc = f32x4{0.f, 0.f, 0.f, 0.f};
#pragma unroll
      for (int r = 0; r < 4; ++r) {
        const int rr = 4 * g + r;
        f32x4 p = P4[rr][c4];
        f32x4 v = rf_l[rr] * (p * fc + outl[rr] * xt);
        P4[rr][c4] = v;
        acc += v;
      }
      SL[g][c4] = acc;
    }
    __syncthreads();

    f32x4* Sp4 = (f32x4*)Spart + (size_t)(t & 1) * NB * N4;
    if (tid < N4) {
      f32x4 s = SL[0][tid] + SL[1][tid] + SL[2][tid] + SL[3][tid];
      f32x4* dst = Sp4 + b * N4 + tid;
      asm volatile("global_store_dwordx4 %0, %1, off sc0 sc1"
                   :: "v"(dst), "v"(s) : "memory");
    }
    __syncthreads();  // each wave drains vmcnt on arrival -> stores at LLC

    // ---- flag barrier: sc-coherent, fence-free ----
    if (w == 0) {
      const unsigned target = t + 1u;
      if (l == 0)
        __hip_atomic_store(&flags[b], target, __ATOMIC_RELAXED,
                           __HIP_MEMORY_SCOPE_AGENT);
      for (;;) {
        unsigned v = __hip_atomic_load(&flags[l], __ATOMIC_RELAXED,
                                       __HIP_MEMORY_SCOPE_AGENT);
        if (__all(v >= target)) break;
        __builtin_amdgcn_s_sleep(1);
      }
    }
    __syncthreads();

    // ---- colsum all-reduce: thread (g,c4) sums bb in [16g,16g+16), LLC loads ----
    {
      f32x4 ssum = f32x4{0.f, 0.f, 0.f, 0.f};
#pragma unroll
      for (int bi = 0; bi < 2; ++bi) {
        f32x4 q[8];
#pragma unroll
        for (int i = 0; i < 8; ++i) {
          const f32x4* ap = Sp4 + (16 * g + 8 * bi + i) * N4 + c4;
          asm volatile("global_load_dwordx4 %0, %1, off sc0 sc1"
                       : "=v"(q[i]) : "v"(ap) : "memory");
        }
        asm volatile("s_waitcnt vmcnt(0)" ::: "memory");
        __builtin_amdgcn_sched_barrier(0);  // rule #18: keep uses after the wait
#pragma unroll
        for (int i = 0; i < 8; ++i) ssum += q[i];
      }
      SL[g][c4] = ssum;
    }
    __syncthreads();
    if (tid < N4) {
      f32x4 s = SL[0][tid] + SL[1][tid] + SL[2][tid] + SL[3][tid];
      f32x4 f;
      f.x = (s.x > 1.0f) ? 1.0f / s.x : 1.0f;  // MAX_PRE = 1
      f.y = (s.y > 1.0f) ? 1.0f / s.y : 1.0f;
      f.z = (s.z > 1.0f) ? 1.0f / s.z : 1.0f;
      f.w = (s.w > 1.0f) ? 1.0f / s.w : 1.0f;
      F4[tid] = f;
    }
    __syncthreads();
  }
}

extern "C" void kernel_launch(void* const* d_in, const int* in_sizes, int n_in,
                              void* d_out, int out_size, void* d_ws, size_t ws_size,
                              hipStream_t stream) {
  const float* X = (const float*)d_in[0];   // inputs [128][1024]
  const float* W = (const float*)d_in[2];   // out_in_fixed [1024][1024]
  float* OUT = (float*)d_out;               // [128][1024] f32

  char* ws = (char*)d_ws;
  float* Spart = (float*)ws;                               // 2*NB*N*4 = 512 KB
  unsigned* flags = (unsigned*)(ws + (size_t)2 * NB * N * 4);

  // flags must start at 0 on every (graph-replayed) launch; ws is poisoned 0xAA
  hipMemsetAsync(flags, 0, NB * sizeof(unsigned), stream);

  hipLaunchKernelGGL(rf_step_kernel, dim3(NB), dim3(NT), 0, stream,
                     X, W, OUT, Spart, flags);
}